// Round 7
// baseline (1775.404 us; speedup 1.0000x reference)
//
#include <hip/hip_runtime.h>

// TiThTe: sequential 3-state thermal RC scan, B=4096 elements, T=8760 steps.
// Round 7 (resubmit — bench was an infra failure, container died twice; no
// counters, no signal; kernel unchanged).
//   R6 post-mortem (MATCHED, 725->498 us): 136 cyc/step, per-active-SIMD
//   VALU issue 71% (~97 cyc) + ~39 cyc stall = exposed serial-chain latency
//   (sub->fma->fma->fma->rsq->mul->fma ~= 44 cyc) that one wave's own
//   independent work can't fully cover under in-order issue.
//   R3's "TLP can't help" was correct only for the latency-bound regime;
//   at 71% issue occupancy a second wave per SIMD fills the bubbles:
//   2 x 97 = 194 cyc demand per 136 window -> VALU pipe saturates ->
//   per-elem-step cost drops toward the ~97-cyc issue floor.
// Changes vs R6 (hot-loop body byte-identical):
//   - 8 blocks x 512 threads (was 64 x 64): 8 waves/block = 2 per SIMD on
//     8 CUs. Total still 64 waves (hard cap: B/64 serial recurrences).
//   - 32-bit store offsets (validated in R5): out < 4 GiB, so unsigned dword
//     index + one v_add_u32 per step replaces the 64-bit pointer increment.
// Resource check: VGPR 2x88/SIMD ok; LDS 26 KB/block; store traffic ~54 B/cyc
// per CU across 8 CUs — under the port limit.

#define CHUNK 2190   // 8760 = 4 * 2190; (2190*3+3)*4 B = 26,292 B LDS
#define NTH   512    // threads per block; 8 waves -> 2 per SIMD

__global__ __launch_bounds__(NTH) void tithte_kernel(
    const float* __restrict__ state0,   // (B,3)
    const float* __restrict__ params,   // (B,6) : C1,R1,C2,R2,C3,R3
    const float* __restrict__ ext,      // (T,3) : T_out, heatPower, solarGains
    const int*   __restrict__ dtp,      // scalar dt
    float*       __restrict__ out,      // (T,B,3)
    int B, int T)
{
    __shared__ float sext[CHUNK * 3 + 3];   // +3: harmless prefetch overread

    const int b = blockIdx.x * blockDim.x + threadIdx.x;

    const float dtf = (float)dtp[0];

    const float C1 = params[b * 6 + 0];
    const float R1 = params[b * 6 + 1];
    const float C2 = params[b * 6 + 2];
    const float R2 = params[b * 6 + 3];
    const float C3 = params[b * 6 + 4];
    const float R3 = params[b * 6 + 5];

    const float k1 = dtf / C1;
    const float k2 = dtf / C2;
    const float k3 = dtf / C3;

    // Coefficients pre-scaled by 1e-5 (y = dT * 1e-5). ulp-level change,
    // validated R5/R6 (passed, absmax 1024.0 vs threshold 3891).
    const float S    = 1.0e-5f;
    const float a11s = (k1 / R1) * S;
    const float a12s = (k1 / R2) * S;
    const float k1s  = k1 * S;
    const float a22s = (k2 / R2) * S;
    const float k2s  = k2 * S;
    const float a31s = (k3 / R1) * S;
    const float a33s = (k3 / R3) * S;

    const float TAME = 100000.0f;

    float Tin  = state0[b * 3 + 0];
    float Th   = state0[b * 3 + 1];
    float Tenv = state0[b * 3 + 2];

    // 32-bit dword offset: max index (8759*4096+4095)*3+2 < 2^27.
    unsigned       ofs = (unsigned)b * 3u;
    const unsigned B3  = (unsigned)B * 3u;

    for (int c = 0; c < T; c += CHUNK) {
        const int n = (T - c < CHUNK) ? (T - c) : CHUNK;

        __syncthreads();   // previous chunk's LDS reads done before overwrite
        for (int i = threadIdx.x; i < n * 3; i += NTH)
            sext[i] = ext[(size_t)c * 3 + i];
        __syncthreads();

        // Software-pipelined ext triple: current step's values already in
        // registers; next step's ds_reads issue before the dependent chain.
        float Tout = sext[0];
        float hp   = sext[1];
        float sg   = sext[2];

#pragma unroll 6
        for (int t = 0; t < n; ++t) {
            // prefetch t+1 (overreads 3 floats past n*3 on last iter: padded)
            const float ToutN = sext[t * 3 + 3];
            const float hpN   = sext[t * 3 + 4];
            const float sgN   = sext[t * 3 + 5];

            // off-chain products (ext values were available last iteration)
            const float k1sg = k1s * sg;
            const float k2hp = k2s * hp;
            const float c3t  = a33s * Tout;

            const float u = Tin - Tenv;
            const float v = Tin - Th;

            const float y1 = fmaf(-a12s, v, fmaf(-a11s, u, k1sg));
            const float y2 = fmaf( a22s, v, k2hp);
            const float y3 = fmaf( a31s, u, fmaf(-a33s, Tenv, c3t));

            const float r1 = __builtin_amdgcn_rsqf(fmaf(y1, y1, 1.0f));
            const float r2 = __builtin_amdgcn_rsqf(fmaf(y2, y2, 1.0f));
            const float r3 = __builtin_amdgcn_rsqf(fmaf(y3, y3, 1.0f));

            Tin  = fmaf(y1 * TAME, r1, Tin);
            Th   = fmaf(y2 * TAME, r2, Th);
            Tenv = fmaf(y3 * TAME, r3, Tenv);

            out[ofs]     = Tin;
            out[ofs + 1] = Th;
            out[ofs + 2] = Tenv;
            ofs += B3;

            Tout = ToutN; hp = hpN; sg = sgN;
        }
    }
}

extern "C" void kernel_launch(void* const* d_in, const int* in_sizes, int n_in,
                              void* d_out, int out_size, void* d_ws, size_t ws_size,
                              hipStream_t stream) {
    const float* state0 = (const float*)d_in[0];
    const float* params = (const float*)d_in[1];
    const float* ext    = (const float*)d_in[2];
    const int*   dtp    = (const int*)d_in[3];
    float*       out    = (float*)d_out;

    const int B = in_sizes[0] / 3;   // 4096
    const int T = in_sizes[2] / 3;   // 8760

    const int block = NTH;
    const int grid  = B / block;     // 8 blocks of 8 waves -> 2 waves/SIMD
    tithte_kernel<<<grid, block, 0, stream>>>(state0, params, ext, dtp, out, B, T);
}